// Round 6
// baseline (395.864 us; speedup 1.0000x reference)
//
#include <hip/hip_runtime.h>
#include <hip/hip_bf16.h>

typedef __attribute__((ext_vector_type(8))) short bf16x8;
typedef __attribute__((ext_vector_type(4))) short bf16x4;
typedef __attribute__((ext_vector_type(4))) float f32x4;

__device__ __forceinline__ unsigned short f2bf(float f) {
  union { float f; unsigned int u; } v; v.f = f;
  unsigned int r = (v.u + 0x7fffu + ((v.u >> 16) & 1u)) >> 16;
  return (unsigned short)r;
}

__device__ __forceinline__ unsigned int pk2bf(float a, float b) {
  float2 t; t.x = a; t.y = b;
  __hip_bfloat162 h = __float22bfloat162_rn(t);
  union { __hip_bfloat162 h; unsigned int u; } cv; cv.h = h;
  return cv.u;
}

__device__ __forceinline__ void g2l16(unsigned short* lds, const unsigned short* g) {
  __builtin_amdgcn_global_load_lds(
      (const __attribute__((address_space(1))) unsigned int*)g,
      (__attribute__((address_space(3))) unsigned int*)lds, 16, 0, 0);
}

// ---------------- prep kernels ----------------

__global__ __launch_bounds__(256) void cast_hs_kernel(const float* __restrict__ in,
                                                      unsigned short* __restrict__ out) {
  size_t i = (size_t)blockIdx.x * 256 + threadIdx.x;
  float4 v = ((const float4*)in)[i];
  ushort4 o;
  o.x = f2bf(v.x); o.y = f2bf(v.y); o.z = f2bf(v.z); o.w = f2bf(v.w);
  ((ushort4*)out)[i] = o;
}

// One launch transposes all four weight matrices. z selects matrix.
// src [2048][N] fp32 -> dst [N][2048] bf16.
__global__ __launch_bounds__(256) void transpose_all_kernel(
    const float* __restrict__ Wq, const float* __restrict__ Wk,
    const float* __restrict__ Wv, const float* __restrict__ Wo,
    unsigned short* __restrict__ Wqkv, unsigned short* __restrict__ WoT) {
  __shared__ float tile[32][33];
  int z = blockIdx.z;
  const float* src; unsigned short* dst; int N;
  if (z == 0)      { src = Wq; dst = Wqkv;                          N = 2048; }
  else if (z == 1) { src = Wk; dst = Wqkv + (size_t)2048 * 2048;    N = 512; }
  else if (z == 2) { src = Wv; dst = Wqkv + (size_t)2560 * 2048;    N = 512; }
  else             { src = Wo; dst = WoT;                           N = 2048; }
  if (blockIdx.x * 32 >= N) return;
  int n0 = blockIdx.x * 32, k0 = blockIdx.y * 32;
  int t = threadIdx.x;
  for (int i = 0; i < 4; ++i) {
    int linear = i * 256 + t;
    int kr = linear >> 5, nc = linear & 31;
    tile[kr][nc] = src[(size_t)(k0 + kr) * N + (n0 + nc)];
  }
  __syncthreads();
  for (int i = 0; i < 4; ++i) {
    int linear = i * 256 + t;
    int nr = linear >> 5, kc = linear & 31;
    dst[(size_t)(n0 + nr) * 2048 + (k0 + kc)] = f2bf(tile[kc][nr]);
  }
}

// ---------------- fused QKV GEMM ----------------
// A: [4096][2048] bf16 (hs). Bt: [3072][2048] bf16 (Wq|Wk|Wv transposed, n-major).
// BK=64, XOR chunk swizzle (c_lds = c_g ^ (row&7)) so the 128B-row-stride LDS
// tile reads stay bank-uniform while g2l16 destinations stay contiguous.
// Q is pre-scaled by 0.125*log2(e) so attention can use exp2 directly.
// Epilogue repacks through LDS, then coalesced 16B stores:
//   Q -> [b][h][s][64], K -> [b][g][s][64], V -> [b][g][d][s] (transposed)

#define QSCALE 0.18033688011112042f  // 0.125 * log2(e)

__global__ __launch_bounds__(256) void gemm_qkv_kernel(
    const unsigned short* __restrict__ A, const unsigned short* __restrict__ Bt,
    const float* __restrict__ bq, const float* __restrict__ bk, const float* __restrict__ bv,
    unsigned short* __restrict__ Qb, unsigned short* __restrict__ Kb,
    unsigned short* __restrict__ Vtb) {
  // 34816 B: epilogue tile [128][136]; first 32 KB double as sA/sB staging
  __shared__ __align__(16) unsigned short smem[128 * 136];
  unsigned short* sA = smem;
  unsigned short* sB = smem + 8192;
  const int K = 2048;
  int bm0 = blockIdx.y * 128, bn0 = blockIdx.x * 128;
  int t = threadIdx.x;
  int w = t >> 6, lane = t & 63, l16 = lane & 15, quad = lane >> 4;
  int wm = (w & 1) * 64, wn = (w >> 1) * 64;
  int x7 = l16 & 7;
  f32x4 zero = {0.f, 0.f, 0.f, 0.f};
  f32x4 acc[4][4];
  for (int mt = 0; mt < 4; ++mt)
    for (int nt = 0; nt < 4; ++nt) acc[mt][nt] = zero;

  for (int k0 = 0; k0 < K; k0 += 64) {
    for (int i = 0; i < 4; ++i) {
      int linear = i * 256 + t;
      int row = linear >> 3, cg = ((linear & 7) ^ (row & 7)) * 8;
      g2l16(sA + linear * 8, A + (size_t)(bm0 + row) * K + k0 + cg);
      g2l16(sB + linear * 8, Bt + (size_t)(bn0 + row) * K + k0 + cg);
    }
    __syncthreads();
    for (int s = 0; s < 2; ++s) {
      bf16x8 af[4], bfr[4];
      int ck = ((s * 4 + quad) ^ x7) * 8;
      for (int mt = 0; mt < 4; ++mt)
        af[mt] = *(const bf16x8*)(sA + (wm + mt * 16 + l16) * 64 + ck);
      for (int nt = 0; nt < 4; ++nt)
        bfr[nt] = *(const bf16x8*)(sB + (wn + nt * 16 + l16) * 64 + ck);
      for (int mt = 0; mt < 4; ++mt)
        for (int nt = 0; nt < 4; ++nt)
          acc[mt][nt] = __builtin_amdgcn_mfma_f32_16x16x32_bf16(af[mt], bfr[nt], acc[mt][nt], 0, 0, 0);
    }
    __syncthreads();
  }

  // ---- epilogue: repack via LDS, coalesced 16B stores ----
  const int SP = 136;
  bool isV = (bn0 >= 2560);
  bool isQ = (bn0 < 2048);
  const float* bias = isQ ? bq : (bn0 < 2560 ? bk : bv);
  int nbase = isQ ? 0 : (bn0 < 2560 ? 2048 : 2560);

  for (int nt = 0; nt < 4; ++nt) {
    int nl = wn + nt * 16 + l16;
    float bb = bias[bn0 + nl - nbase];
    for (int mt = 0; mt < 4; ++mt)
      for (int r = 0; r < 4; ++r) {
        int ml = wm + mt * 16 + quad * 4 + r;
        float fv = acc[mt][nt][r] + bb;
        if (isQ) fv *= QSCALE;
        unsigned short val = f2bf(fv);
        if (isV) smem[nl * SP + ml] = val;   // transposed tile [n][m]
        else     smem[ml * SP + nl] = val;   // row-major tile [m][n]
      }
  }
  __syncthreads();

  int b = bm0 >> 11, s0 = bm0 & 2047;
  if (bn0 < 2048) {            // Q -> [b][h][s][64]
    for (int i = 0; i < 8; ++i) {
      int idx = i * 256 + t;
      int sub = idx >> 10, s_l = (idx >> 3) & 127, dch = (idx & 7) * 8;
      bf16x8 v = *(const bf16x8*)(smem + s_l * SP + sub * 64 + dch);
      int n = bn0 + sub * 64 + dch;
      int h = n >> 6, d = n & 63;
      *(bf16x8*)(Qb + (((size_t)b * 32 + h) * 2048 + s0 + s_l) * 64 + d) = v;
    }
  } else if (bn0 < 2560) {     // K -> [b][g][s][64]
    for (int i = 0; i < 8; ++i) {
      int idx = i * 256 + t;
      int sub = idx >> 10, s_l = (idx >> 3) & 127, dch = (idx & 7) * 8;
      bf16x8 v = *(const bf16x8*)(smem + s_l * SP + sub * 64 + dch);
      int nn = bn0 + sub * 64 + dch - 2048;
      int g = nn >> 6, d = nn & 63;
      *(bf16x8*)(Kb + (((size_t)b * 8 + g) * 2048 + s0 + s_l) * 64 + d) = v;
    }
  } else {                     // V -> [b][g][d][s] (transposed)
    for (int i = 0; i < 8; ++i) {
      int idx = i * 256 + t;
      int nl = idx >> 4, sj = (idx & 15) * 8;
      bf16x8 v = *(const bf16x8*)(smem + nl * SP + sj);
      int nn = bn0 + nl - 2560;
      int g = nn >> 6, d = nn & 63;
      *(bf16x8*)(Vtb + (((size_t)b * 8 + g) * 64 + d) * 2048 + s0 + sj) = v;
    }
  }
}

// ---------------- flash attention ----------------
// grid: (S/64, NUM_HEAD, B), block 256 (4 waves, 16 q-rows each)
// KB=128 keys per iteration (16 iters): halves barrier/vmcnt drains, 8 nt-steps
// of independent MFMA work per barrier for ILP.
// S^T = K @ Q^T via mfma_16x16x32 (swapped operands): C-layout q-row = l16,
// key = quad*4+reg == A-operand layout of mfma_f32_16x16x16bf16_1k, so P stays
// in registers (exp2 + pack, no LDS round-trip). V^T b64 fragments from the
// chunk-interleaved Vt tile are bank-balanced.
// Q was pre-scaled by 0.125*log2(e); p = exp2(s' - 10) (exact softmax shift).

__global__ __launch_bounds__(256) void attn_kernel(
    const unsigned short* __restrict__ Qb, const unsigned short* __restrict__ Kb,
    const unsigned short* __restrict__ Vtb, unsigned short* __restrict__ AttnB) {
  __shared__ __align__(16) unsigned short Kt[8 * 128 * 8];   // [dchunk][key][8]
  __shared__ __align__(16) unsigned short Vt[16 * 64 * 8];   // [keychunk][d][8]
  int qt = blockIdx.x, h = blockIdx.y, b = blockIdx.z;
  int g = h >> 2;
  int t = threadIdx.x, w = t >> 6, lane = t & 63, l16 = lane & 15, quad = lane >> 4;

  const unsigned short* qbase =
      Qb + (((size_t)b * 32 + h) * 2048 + qt * 64 + w * 16 + l16) * 64 + quad * 8;
  bf16x8 aQ0 = *(const bf16x8*)(qbase);
  bf16x8 aQ1 = *(const bf16x8*)(qbase + 32);

  const unsigned short* kbase = Kb + ((size_t)b * 8 + g) * (2048 * 64);
  const unsigned short* vbase = Vtb + ((size_t)b * 8 + g) * (64 * 2048);

  float l_acc = 0.f;                  // per-lane partial of l[row = l16]
  f32x4 zero = {0.f, 0.f, 0.f, 0.f};
  f32x4 o[4];                         // o[dtile]: row(q) = quad*4+reg, col(d) = l16
  for (int dt = 0; dt < 4; ++dt) o[dt] = zero;

  for (int kb = 0; kb < 16; ++kb) {
    for (int i = 0; i < 4; ++i) {
      int linear = i * 256 + t;
      int krow = linear & 127, kc = linear >> 7;     // K tile: 128 keys x 8 chunks
      g2l16(Kt + linear * 8, kbase + (size_t)(kb * 128 + krow) * 64 + kc * 8);
      int vd = linear & 63, vc = linear >> 6;        // V tile: 16 keychunks x 64 d
      g2l16(Vt + linear * 8, vbase + (size_t)vd * 2048 + kb * 128 + vc * 8);
    }
    __syncthreads();

    for (int nt = 0; nt < 8; ++nt) {
      // S^T(16 keys x 16 qrows) = K_nt @ Q^T
      bf16x8 bk0 = *(const bf16x8*)(Kt + (quad * 128 + nt * 16 + l16) * 8);
      bf16x8 bk1 = *(const bf16x8*)(Kt + ((quad + 4) * 128 + nt * 16 + l16) * 8);
      f32x4 st = __builtin_amdgcn_mfma_f32_16x16x32_bf16(bk0, aQ0, zero, 0, 0, 0);
      st = __builtin_amdgcn_mfma_f32_16x16x32_bf16(bk1, aQ1, st, 0, 0, 0);

      // p = 2^(s' - 10); per-lane l partial (row = l16)
      float p0 = __builtin_amdgcn_exp2f(st[0] - 10.0f);
      float p1 = __builtin_amdgcn_exp2f(st[1] - 10.0f);
      float p2 = __builtin_amdgcn_exp2f(st[2] - 10.0f);
      float p3 = __builtin_amdgcn_exp2f(st[3] - 10.0f);
      l_acc += (p0 + p1) + (p2 + p3);

      // pack to A-fragment of 16x16x16 (m = l16, k = quad*4+j)
      union { unsigned int u[2]; bf16x4 v; } pa;
      pa.u[0] = pk2bf(p0, p1);
      pa.u[1] = pk2bf(p2, p3);

      // PV: O[dt] += P_nt @ V; B-frag = V^T[d = dt*16+l16][key = nt*16+quad*4+j]
      int c = nt * 2 + (quad >> 1);
      int ho = (quad & 1) * 4;
      for (int dt = 0; dt < 4; ++dt) {
        bf16x4 bv = *(const bf16x4*)(Vt + (c * 64 + dt * 16 + l16) * 8 + ho);
        o[dt] = __builtin_amdgcn_mfma_f32_16x16x16bf16_1k(pa.v, bv, o[dt], 0, 0, 0);
      }
    }
    __syncthreads();
  }

  // reduce l across quads (lanes l16, l16+16, l16+32, l16+48 hold same row)
  l_acc += __shfl_xor(l_acc, 16);
  l_acc += __shfl_xor(l_acc, 32);

  for (int r = 0; r < 4; ++r) {
    float lr = __shfl(l_acc, quad * 4 + r);   // l for output row quad*4+r
    float inv = 1.f / lr;
    int srow = qt * 64 + w * 16 + quad * 4 + r;
    size_t base = ((size_t)b * 2048 + srow) * 2048 + h * 64;
    for (int dt = 0; dt < 4; ++dt)
      AttnB[base + dt * 16 + l16] = f2bf(o[dt][r] * inv);
  }
}

// ---------------- output GEMM ----------------
// A: AttnB [4096][2048] bf16, Bt: WoT [2048][2048] bf16, out fp32 + bias
// BK=64 with XOR chunk swizzle (see gemm_qkv).

__global__ __launch_bounds__(256) void gemm_out_kernel(
    const unsigned short* __restrict__ A, const unsigned short* __restrict__ Bt,
    const float* __restrict__ bo, float* __restrict__ out) {
  __shared__ __align__(16) unsigned short sA[128 * 64];
  __shared__ __align__(16) unsigned short sB[128 * 64];
  const int K = 2048;
  int bm0 = blockIdx.y * 128, bn0 = blockIdx.x * 128;
  int t = threadIdx.x;
  int w = t >> 6, lane = t & 63, l16 = lane & 15, quad = lane >> 4;
  int wm = (w & 1) * 64, wn = (w >> 1) * 64;
  int x7 = l16 & 7;
  f32x4 zero = {0.f, 0.f, 0.f, 0.f};
  f32x4 acc[4][4];
  for (int mt = 0; mt < 4; ++mt)
    for (int nt = 0; nt < 4; ++nt) acc[mt][nt] = zero;

  for (int k0 = 0; k0 < K; k0 += 64) {
    for (int i = 0; i < 4; ++i) {
      int linear = i * 256 + t;
      int row = linear >> 3, cg = ((linear & 7) ^ (row & 7)) * 8;
      g2l16(sA + linear * 8, A + (size_t)(bm0 + row) * K + k0 + cg);
      g2l16(sB + linear * 8, Bt + (size_t)(bn0 + row) * K + k0 + cg);
    }
    __syncthreads();
    for (int s = 0; s < 2; ++s) {
      bf16x8 af[4], bfr[4];
      int ck = ((s * 4 + quad) ^ x7) * 8;
      for (int mt = 0; mt < 4; ++mt)
        af[mt] = *(const bf16x8*)(sA + (wm + mt * 16 + l16) * 64 + ck);
      for (int nt = 0; nt < 4; ++nt)
        bfr[nt] = *(const bf16x8*)(sB + (wn + nt * 16 + l16) * 64 + ck);
      for (int mt = 0; mt < 4; ++mt)
        for (int nt = 0; nt < 4; ++nt)
          acc[mt][nt] = __builtin_amdgcn_mfma_f32_16x16x32_bf16(af[mt], bfr[nt], acc[mt][nt], 0, 0, 0);
    }
    __syncthreads();
  }

  for (int nt = 0; nt < 4; ++nt) {
    int n = bn0 + wn + nt * 16 + l16;
    float bias = bo[n];
    for (int mt = 0; mt < 4; ++mt)
      for (int r = 0; r < 4; ++r) {
        int m = bm0 + wm + mt * 16 + quad * 4 + r;
        out[(size_t)m * 2048 + n] = acc[mt][nt][r] + bias;
      }
  }
}

// ---------------- launch ----------------

extern "C" void kernel_launch(void* const* d_in, const int* in_sizes, int n_in,
                              void* d_out, int out_size, void* d_ws, size_t ws_size,
                              hipStream_t stream) {
  const float* hs = (const float*)d_in[0];
  const float* Wq = (const float*)d_in[1];
  const float* bq = (const float*)d_in[2];
  const float* Wk = (const float*)d_in[3];
  const float* bk = (const float*)d_in[4];
  const float* Wv = (const float*)d_in[5];
  const float* bv = (const float*)d_in[6];
  const float* Wo = (const float*)d_in[7];
  const float* bo = (const float*)d_in[8];
  float* out = (float*)d_out;

  char* ws = (char*)d_ws;
  unsigned short* hsb   = (unsigned short*)(ws);                 // 16 MB  [4096][2048]
  unsigned short* Wqkv  = (unsigned short*)(ws + 16777216);      // 12 MB  [3072][2048]
  unsigned short* WoT   = (unsigned short*)(ws + 29360128);      // 8 MB   [2048][2048]
  unsigned short* Qb    = (unsigned short*)(ws + 37748736);      // 16 MB  [2][32][2048][64]
  unsigned short* Kb    = (unsigned short*)(ws + 54525952);      // 4 MB   [2][8][2048][64]
  unsigned short* Vtb   = (unsigned short*)(ws + 58720256);      // 4 MB   [2][8][64][2048]
  unsigned short* AttnB = (unsigned short*)(ws + 62914560);      // 16 MB  [4096][2048]

  hipLaunchKernelGGL(cast_hs_kernel, dim3(8192), dim3(256), 0, stream, hs, hsb);
  hipLaunchKernelGGL(transpose_all_kernel, dim3(64, 64, 4), dim3(256), 0, stream,
                     Wq, Wk, Wv, Wo, Wqkv, WoT);
  hipLaunchKernelGGL(gemm_qkv_kernel, dim3(24, 32), dim3(256), 0, stream,
                     hsb, Wqkv, bq, bk, bv, Qb, Kb, Vtb);
  hipLaunchKernelGGL(attn_kernel, dim3(32, 32, 2), dim3(256), 0, stream, Qb, Kb, Vtb, AttnB);
  hipLaunchKernelGGL(gemm_out_kernel, dim3(16, 32), dim3(256), 0, stream, AttnB, WoT, bo, out);
}

// Round 7
// 340.940 us; speedup vs baseline: 1.1611x; 1.1611x over previous
//
#include <hip/hip_runtime.h>
#include <hip/hip_bf16.h>

typedef __attribute__((ext_vector_type(8))) short bf16x8;
typedef __attribute__((ext_vector_type(4))) short bf16x4;
typedef __attribute__((ext_vector_type(4))) float f32x4;

__device__ __forceinline__ unsigned short f2bf(float f) {
  union { float f; unsigned int u; } v; v.f = f;
  unsigned int r = (v.u + 0x7fffu + ((v.u >> 16) & 1u)) >> 16;
  return (unsigned short)r;
}

__device__ __forceinline__ unsigned int pk2bf(float a, float b) {
  float2 t; t.x = a; t.y = b;
  __hip_bfloat162 h = __float22bfloat162_rn(t);
  union { __hip_bfloat162 h; unsigned int u; } cv; cv.h = h;
  return cv.u;
}

__device__ __forceinline__ void g2l16(unsigned short* lds, const unsigned short* g) {
  __builtin_amdgcn_global_load_lds(
      (const __attribute__((address_space(1))) unsigned int*)g,
      (__attribute__((address_space(3))) unsigned int*)lds, 16, 0, 0);
}

// ---------------- prep kernels ----------------

__global__ __launch_bounds__(256) void cast_hs_kernel(const float* __restrict__ in,
                                                      unsigned short* __restrict__ out) {
  size_t i = (size_t)blockIdx.x * 256 + threadIdx.x;
  float4 v = ((const float4*)in)[i];
  ushort4 o;
  o.x = f2bf(v.x); o.y = f2bf(v.y); o.z = f2bf(v.z); o.w = f2bf(v.w);
  ((ushort4*)out)[i] = o;
}

// One launch transposes all four weight matrices. z selects matrix.
// src [2048][N] fp32 -> dst [N][2048] bf16.
__global__ __launch_bounds__(256) void transpose_all_kernel(
    const float* __restrict__ Wq, const float* __restrict__ Wk,
    const float* __restrict__ Wv, const float* __restrict__ Wo,
    unsigned short* __restrict__ Wqkv, unsigned short* __restrict__ WoT) {
  __shared__ float tile[32][33];
  int z = blockIdx.z;
  const float* src; unsigned short* dst; int N;
  if (z == 0)      { src = Wq; dst = Wqkv;                          N = 2048; }
  else if (z == 1) { src = Wk; dst = Wqkv + (size_t)2048 * 2048;    N = 512; }
  else if (z == 2) { src = Wv; dst = Wqkv + (size_t)2560 * 2048;    N = 512; }
  else             { src = Wo; dst = WoT;                           N = 2048; }
  if (blockIdx.x * 32 >= N) return;
  int n0 = blockIdx.x * 32, k0 = blockIdx.y * 32;
  int t = threadIdx.x;
  for (int i = 0; i < 4; ++i) {
    int linear = i * 256 + t;
    int kr = linear >> 5, nc = linear & 31;
    tile[kr][nc] = src[(size_t)(k0 + kr) * N + (n0 + nc)];
  }
  __syncthreads();
  for (int i = 0; i < 4; ++i) {
    int linear = i * 256 + t;
    int nr = linear >> 5, kc = linear & 31;
    dst[(size_t)(n0 + nr) * 2048 + (k0 + kc)] = f2bf(tile[kc][nr]);
  }
}

// ---------------- fused QKV GEMM (R5 body, BK=32) ----------------
// A: [4096][2048] bf16 (hs). Bt: [3072][2048] bf16 (Wq|Wk|Wv transposed, n-major).
// Q is pre-scaled by 0.125*log2(e) so attention can use exp2 directly.
// Epilogue repacks through LDS, then coalesced 16B stores:
//   Q -> [b][h][s][64], K -> [b][g][s][64], V -> [b][g][d][s] (transposed)

#define QSCALE 0.18033688011112042f  // 0.125 * log2(e)

__global__ __launch_bounds__(256) void gemm_qkv_kernel(
    const unsigned short* __restrict__ A, const unsigned short* __restrict__ Bt,
    const float* __restrict__ bq, const float* __restrict__ bk, const float* __restrict__ bv,
    unsigned short* __restrict__ Qb, unsigned short* __restrict__ Kb,
    unsigned short* __restrict__ Vtb) {
  __shared__ __align__(16) unsigned short smem[128 * 136];
  unsigned short* sA = smem;
  unsigned short* sB = smem + 4096;
  const int K = 2048;
  int bm0 = blockIdx.y * 128, bn0 = blockIdx.x * 128;
  int t = threadIdx.x;
  int w = t >> 6, lane = t & 63, l16 = lane & 15, quad = lane >> 4;
  int wm = (w & 1) * 64, wn = (w >> 1) * 64;
  f32x4 zero = {0.f, 0.f, 0.f, 0.f};
  f32x4 acc[4][4];
  for (int mt = 0; mt < 4; ++mt)
    for (int nt = 0; nt < 4; ++nt) acc[mt][nt] = zero;

  for (int k0 = 0; k0 < K; k0 += 32) {
    for (int i = 0; i < 2; ++i) {
      int linear = i * 256 + t;
      int row = linear >> 2, kofs = (linear & 3) * 8;
      g2l16(sA + linear * 8, A + (size_t)(bm0 + row) * K + k0 + kofs);
      g2l16(sB + linear * 8, Bt + (size_t)(bn0 + row) * K + k0 + kofs);
    }
    __syncthreads();
    bf16x8 af[4], bfr[4];
    for (int mt = 0; mt < 4; ++mt)
      af[mt] = *(const bf16x8*)(sA + (wm + mt * 16 + l16) * 32 + quad * 8);
    for (int nt = 0; nt < 4; ++nt)
      bfr[nt] = *(const bf16x8*)(sB + (wn + nt * 16 + l16) * 32 + quad * 8);
    for (int mt = 0; mt < 4; ++mt)
      for (int nt = 0; nt < 4; ++nt)
        acc[mt][nt] = __builtin_amdgcn_mfma_f32_16x16x32_bf16(af[mt], bfr[nt], acc[mt][nt], 0, 0, 0);
    __syncthreads();
  }

  const int SP = 136;
  bool isV = (bn0 >= 2560);
  bool isQ = (bn0 < 2048);
  const float* bias = isQ ? bq : (bn0 < 2560 ? bk : bv);
  int nbase = isQ ? 0 : (bn0 < 2560 ? 2048 : 2560);

  for (int nt = 0; nt < 4; ++nt) {
    int nl = wn + nt * 16 + l16;
    float bb = bias[bn0 + nl - nbase];
    for (int mt = 0; mt < 4; ++mt)
      for (int r = 0; r < 4; ++r) {
        int ml = wm + mt * 16 + quad * 4 + r;
        float fv = acc[mt][nt][r] + bb;
        if (isQ) fv *= QSCALE;
        unsigned short val = f2bf(fv);
        if (isV) smem[nl * SP + ml] = val;
        else     smem[ml * SP + nl] = val;
      }
  }
  __syncthreads();

  int b = bm0 >> 11, s0 = bm0 & 2047;
  if (bn0 < 2048) {            // Q -> [b][h][s][64]
    for (int i = 0; i < 8; ++i) {
      int idx = i * 256 + t;
      int sub = idx >> 10, s_l = (idx >> 3) & 127, dch = (idx & 7) * 8;
      bf16x8 v = *(const bf16x8*)(smem + s_l * SP + sub * 64 + dch);
      int n = bn0 + sub * 64 + dch;
      int h = n >> 6, d = n & 63;
      *(bf16x8*)(Qb + (((size_t)b * 32 + h) * 2048 + s0 + s_l) * 64 + d) = v;
    }
  } else if (bn0 < 2560) {     // K -> [b][g][s][64]
    for (int i = 0; i < 8; ++i) {
      int idx = i * 256 + t;
      int sub = idx >> 10, s_l = (idx >> 3) & 127, dch = (idx & 7) * 8;
      bf16x8 v = *(const bf16x8*)(smem + s_l * SP + sub * 64 + dch);
      int nn = bn0 + sub * 64 + dch - 2048;
      int g = nn >> 6, d = nn & 63;
      *(bf16x8*)(Kb + (((size_t)b * 8 + g) * 2048 + s0 + s_l) * 64 + d) = v;
    }
  } else {                     // V -> [b][g][d][s] (transposed)
    for (int i = 0; i < 8; ++i) {
      int idx = i * 256 + t;
      int nl = idx >> 4, sj = (idx & 15) * 8;
      bf16x8 v = *(const bf16x8*)(smem + nl * SP + sj);
      int nn = bn0 + nl - 2560;
      int g = nn >> 6, d = nn & 63;
      *(bf16x8*)(Vtb + (((size_t)b * 8 + g) * 64 + d) * 2048 + s0 + sj) = v;
    }
  }
}

// ---------------- flash attention ----------------
// grid: (S/128, NUM_HEAD, B), block 256 (4 waves). Each wave handles TWO
// 16-row q-tiles (rows w*16.. and 64+w*16..) -> K/V ds_reads, staging and
// barriers per score are halved vs the 64-row block.
// KB=64 keys/iter, 16 KB LDS (R5's 65%-occupancy config).
// S^T = K @ Q^T (swapped 16x16x32): C-layout q-row = l16, key = quad*4+reg ==
// A-operand layout of mfma_f32_16x16x16bf16_1k -> P stays in registers.
// VALU cuts: the -10 exp-shift is folded into the S^T accumulator init;
// l is computed by an extra ones-operand 16x16x16 MFMA (no adds, no final
// shuffles -- ol[r] is directly the row sum).
// Q was pre-scaled by 0.125*log2(e); p = exp2(K.Q - 10) (exact softmax shift).

__global__ __launch_bounds__(256) void attn_kernel(
    const unsigned short* __restrict__ Qb, const unsigned short* __restrict__ Kb,
    const unsigned short* __restrict__ Vtb, unsigned short* __restrict__ AttnB) {
  __shared__ __align__(16) unsigned short Kt[64 * 64];   // [dchunk][key][8]
  __shared__ __align__(16) unsigned short Vt[64 * 64];   // [keychunk][d][8]
  int qt = blockIdx.x, h = blockIdx.y, b = blockIdx.z;
  int g = h >> 2;
  int t = threadIdx.x, w = t >> 6, lane = t & 63, l16 = lane & 15, quad = lane >> 4;

  const unsigned short* qb0 =
      Qb + (((size_t)b * 32 + h) * 2048 + qt * 128 + w * 16 + l16) * 64 + quad * 8;
  const unsigned short* qb1 = qb0 + (size_t)64 * 64;
  bf16x8 aQ0a = *(const bf16x8*)(qb0);
  bf16x8 aQ1a = *(const bf16x8*)(qb0 + 32);
  bf16x8 aQ0b = *(const bf16x8*)(qb1);
  bf16x8 aQ1b = *(const bf16x8*)(qb1 + 32);

  const unsigned short* kbase = Kb + ((size_t)b * 8 + g) * (2048 * 64);
  const unsigned short* vbase = Vtb + ((size_t)b * 8 + g) * (64 * 2048);

  f32x4 zero = {0.f, 0.f, 0.f, 0.f};
  f32x4 m10 = {-10.f, -10.f, -10.f, -10.f};
  union { unsigned short s[4]; bf16x4 v; } ones;
  ones.s[0] = 0x3F80; ones.s[1] = 0x3F80; ones.s[2] = 0x3F80; ones.s[3] = 0x3F80;

  f32x4 oA[4], oB[4], olA, olB;
  for (int dt = 0; dt < 4; ++dt) { oA[dt] = zero; oB[dt] = zero; }
  olA = zero; olB = zero;

  for (int kb = 0; kb < 32; ++kb) {
    for (int i = 0; i < 2; ++i) {
      int linear = i * 256 + t;
      int row = linear & 63, c = linear >> 6;
      g2l16(Kt + linear * 8, kbase + (size_t)(kb * 64 + row) * 64 + c * 8);
      g2l16(Vt + linear * 8, vbase + (size_t)row * 2048 + kb * 64 + c * 8);
    }
    __syncthreads();

    for (int nt = 0; nt < 4; ++nt) {
      // S^T(16 keys x 16 qrows) = K_nt @ Q^T, acc pre-seeded with -10
      bf16x8 bk0 = *(const bf16x8*)(Kt + (quad * 64 + nt * 16 + l16) * 8);
      bf16x8 bk1 = *(const bf16x8*)(Kt + ((quad + 4) * 64 + nt * 16 + l16) * 8);
      f32x4 stA = __builtin_amdgcn_mfma_f32_16x16x32_bf16(bk0, aQ0a, m10, 0, 0, 0);
      stA = __builtin_amdgcn_mfma_f32_16x16x32_bf16(bk1, aQ1a, stA, 0, 0, 0);
      f32x4 stB = __builtin_amdgcn_mfma_f32_16x16x32_bf16(bk0, aQ0b, m10, 0, 0, 0);
      stB = __builtin_amdgcn_mfma_f32_16x16x32_bf16(bk1, aQ1b, stB, 0, 0, 0);

      union { unsigned int u[2]; bf16x4 v; } paA, paB;
      paA.u[0] = pk2bf(__builtin_amdgcn_exp2f(stA[0]), __builtin_amdgcn_exp2f(stA[1]));
      paA.u[1] = pk2bf(__builtin_amdgcn_exp2f(stA[2]), __builtin_amdgcn_exp2f(stA[3]));
      paB.u[0] = pk2bf(__builtin_amdgcn_exp2f(stB[0]), __builtin_amdgcn_exp2f(stB[1]));
      paB.u[1] = pk2bf(__builtin_amdgcn_exp2f(stB[2]), __builtin_amdgcn_exp2f(stB[3]));

      // l += P @ ones  (row sums, C-layout rows = quad*4+r)
      olA = __builtin_amdgcn_mfma_f32_16x16x16bf16_1k(paA.v, ones.v, olA, 0, 0, 0);
      olB = __builtin_amdgcn_mfma_f32_16x16x16bf16_1k(paB.v, ones.v, olB, 0, 0, 0);

      // PV: O[dt] += P_nt @ V
      int c = nt * 2 + (quad >> 1);
      int ho = (quad & 1) * 4;
      for (int dt = 0; dt < 4; ++dt) {
        bf16x4 bv = *(const bf16x4*)(Vt + (c * 64 + dt * 16 + l16) * 8 + ho);
        oA[dt] = __builtin_amdgcn_mfma_f32_16x16x16bf16_1k(paA.v, bv, oA[dt], 0, 0, 0);
        oB[dt] = __builtin_amdgcn_mfma_f32_16x16x16bf16_1k(paB.v, bv, oB[dt], 0, 0, 0);
      }
    }
    __syncthreads();
  }

  for (int r = 0; r < 4; ++r) {
    float invA = 1.f / olA[r];
    float invB = 1.f / olB[r];
    int srow0 = qt * 128 + w * 16 + quad * 4 + r;
    size_t base0 = ((size_t)b * 2048 + srow0) * 2048 + h * 64;
    size_t base1 = base0 + (size_t)64 * 2048;
    for (int dt = 0; dt < 4; ++dt) {
      AttnB[base0 + dt * 16 + l16] = f2bf(oA[dt][r] * invA);
      AttnB[base1 + dt * 16 + l16] = f2bf(oB[dt][r] * invB);
    }
  }
}

// ---------------- output GEMM (R5 body, BK=32) ----------------
// A: AttnB [4096][2048] bf16, Bt: WoT [2048][2048] bf16, out fp32 + bias

__global__ __launch_bounds__(256) void gemm_out_kernel(
    const unsigned short* __restrict__ A, const unsigned short* __restrict__ Bt,
    const float* __restrict__ bo, float* __restrict__ out) {
  __shared__ __align__(16) unsigned short sA[128 * 32];
  __shared__ __align__(16) unsigned short sB[128 * 32];
  const int K = 2048;
  int bm0 = blockIdx.y * 128, bn0 = blockIdx.x * 128;
  int t = threadIdx.x;
  int w = t >> 6, lane = t & 63, l16 = lane & 15, quad = lane >> 4;
  int wm = (w & 1) * 64, wn = (w >> 1) * 64;
  f32x4 zero = {0.f, 0.f, 0.f, 0.f};
  f32x4 acc[4][4];
  for (int mt = 0; mt < 4; ++mt)
    for (int nt = 0; nt < 4; ++nt) acc[mt][nt] = zero;

  for (int k0 = 0; k0 < K; k0 += 32) {
    for (int i = 0; i < 2; ++i) {
      int linear = i * 256 + t;
      int row = linear >> 2, kofs = (linear & 3) * 8;
      g2l16(sA + linear * 8, A + (size_t)(bm0 + row) * K + k0 + kofs);
      g2l16(sB + linear * 8, Bt + (size_t)(bn0 + row) * K + k0 + kofs);
    }
    __syncthreads();
    bf16x8 af[4], bfr[4];
    for (int mt = 0; mt < 4; ++mt)
      af[mt] = *(const bf16x8*)(sA + (wm + mt * 16 + l16) * 32 + quad * 8);
    for (int nt = 0; nt < 4; ++nt)
      bfr[nt] = *(const bf16x8*)(sB + (wn + nt * 16 + l16) * 32 + quad * 8);
    for (int mt = 0; mt < 4; ++mt)
      for (int nt = 0; nt < 4; ++nt)
        acc[mt][nt] = __builtin_amdgcn_mfma_f32_16x16x32_bf16(af[mt], bfr[nt], acc[mt][nt], 0, 0, 0);
    __syncthreads();
  }

  for (int nt = 0; nt < 4; ++nt) {
    int n = bn0 + wn + nt * 16 + l16;
    float bias = bo[n];
    for (int mt = 0; mt < 4; ++mt)
      for (int r = 0; r < 4; ++r) {
        int m = bm0 + wm + mt * 16 + quad * 4 + r;
        out[(size_t)m * 2048 + n] = acc[mt][nt][r] + bias;
      }
  }
}

// ---------------- launch ----------------

extern "C" void kernel_launch(void* const* d_in, const int* in_sizes, int n_in,
                              void* d_out, int out_size, void* d_ws, size_t ws_size,
                              hipStream_t stream) {
  const float* hs = (const float*)d_in[0];
  const float* Wq = (const float*)d_in[1];
  const float* bq = (const float*)d_in[2];
  const float* Wk = (const float*)d_in[3];
  const float* bk = (const float*)d_in[4];
  const float* Wv = (const float*)d_in[5];
  const float* bv = (const float*)d_in[6];
  const float* Wo = (const float*)d_in[7];
  const float* bo = (const float*)d_in[8];
  float* out = (float*)d_out;

  char* ws = (char*)d_ws;
  unsigned short* hsb   = (unsigned short*)(ws);                 // 16 MB  [4096][2048]
  unsigned short* Wqkv  = (unsigned short*)(ws + 16777216);      // 12 MB  [3072][2048]
  unsigned short* WoT   = (unsigned short*)(ws + 29360128);      // 8 MB   [2048][2048]
  unsigned short* Qb    = (unsigned short*)(ws + 37748736);      // 16 MB  [2][32][2048][64]
  unsigned short* Kb    = (unsigned short*)(ws + 54525952);      // 4 MB   [2][8][2048][64]
  unsigned short* Vtb   = (unsigned short*)(ws + 58720256);      // 4 MB   [2][8][64][2048]
  unsigned short* AttnB = (unsigned short*)(ws + 62914560);      // 16 MB  [4096][2048]

  hipLaunchKernelGGL(cast_hs_kernel, dim3(8192), dim3(256), 0, stream, hs, hsb);
  hipLaunchKernelGGL(transpose_all_kernel, dim3(64, 64, 4), dim3(256), 0, stream,
                     Wq, Wk, Wv, Wo, Wqkv, WoT);
  hipLaunchKernelGGL(gemm_qkv_kernel, dim3(24, 32), dim3(256), 0, stream,
                     hsb, Wqkv, bq, bk, bv, Qb, Kb, Vtb);
  hipLaunchKernelGGL(attn_kernel, dim3(16, 32, 2), dim3(256), 0, stream, Qb, Kb, Vtb, AttnB);
  hipLaunchKernelGGL(gemm_out_kernel, dim3(16, 32), dim3(256), 0, stream, AttnB, WoT, bo, out);
}